// Round 4
// baseline (109306.519 us; speedup 1.0000x reference)
//
#include <hip/hip_runtime.h>
#include <math.h>

#define NN 1600
#define MAXD 500
#define TS 500
#define NBATCH 4
#define GBLK 25
#define WAVES 4
#define NWAVE (GBLK * WAVES)   // 100 waves
#define RPW 16                 // rows per wave
#define DT 0.05f

// ---------------- workspace layout (floats) ----------------
// cnt   : [0       , 800000)   N*MAXD delay-count weights
// Hc    : [800000  , 1600000)  circular history, head h (logical d -> (h+d)%MAXD)
// deT   : [1600000 , 1603200)  double-buffered delayed_E (2 * N)
// flags : float offset 1603200, NWAVE u32, DENSE (7 cache lines)

#define ATLF(p)    __hip_atomic_load((p), __ATOMIC_RELAXED, __HIP_MEMORY_SCOPE_AGENT)
#define ATSF(p,v)  __hip_atomic_store((p), (v), __ATOMIC_RELAXED, __HIP_MEMORY_SCOPE_AGENT)
#define ATLU(p)    __hip_atomic_load((p), __ATOMIC_RELAXED, __HIP_MEMORY_SCOPE_AGENT)
#define ATSU(p,v)  __hip_atomic_store((p), (v), __ATOMIC_RELAXED, __HIP_MEMORY_SCOPE_AGENT)

__device__ __forceinline__ float h_tf_dev(float a, float b, float d, float c) {
    float u   = a * c - b;
    float num = 1e-5f + fabsf(u);
    float den = 1e-5f * d + fabsf(1.0f - expf(-d * u));
    return num / (den + 1e-8f);
}

__global__ void cnt_kernel(const int* __restrict__ delays, float* __restrict__ cnt) {
    __shared__ int hist[MAXD];
    const int i = blockIdx.x;
    for (int d = threadIdx.x; d < MAXD; d += blockDim.x) hist[d] = 0;
    __syncthreads();
    const int* row = delays + (size_t)i * NN;
    for (int j = threadIdx.x; j < NN; j += blockDim.x) atomicAdd(&hist[row[j]], 1);
    __syncthreads();
    for (int d = threadIdx.x; d < MAXD; d += blockDim.x)
        cnt[(size_t)i * MAXD + d] = (float)hist[d];
}

__global__ void init_kernel(const float* __restrict__ hE, const float* __restrict__ cnt,
                            float* __restrict__ Hc, float* deT, unsigned int* flags) {
    const int i = blockIdx.x;     // one wave per row
    const int lane = threadIdx.x; // 64 threads
    float s = 0.f;
    for (int d = lane; d < MAXD; d += 64) {
        float v = hE[(size_t)i * MAXD + d];
        Hc[(size_t)i * MAXD + d] = v;
        s = fmaf(cnt[(size_t)i * MAXD + d], v, s);
    }
    #pragma unroll
    for (int off = 32; off; off >>= 1) s += __shfl_xor(s, off);
    if (lane == 0) ATSF(&deT[i], s / 1600.0f);   // epoch-0 data into slot 0
    if (i == 0 && lane < NWAVE) ATSU(&flags[lane], 0u);
}

__global__ __launch_bounds__(256, 1) void dmf_main(
        const float* __restrict__ x0, const float* __restrict__ L,
        const float* __restrict__ theta, const float* __restrict__ noise,
        float* __restrict__ out, const float* __restrict__ cnt,
        float* __restrict__ Hc, float* deT, unsigned int* flags) {
    const int lane = threadIdx.x & 63;
    const int wv   = __builtin_amdgcn_readfirstlane(threadIdx.x >> 6);
    const int widx = blockIdx.x * WAVES + wv;   // 0..99
    const int base = widx * RPW;                // first row of this wave (SGPR)

    const float std_in = theta[0],  W_E = theta[1],  tau_E = theta[2], gamma_E = theta[3];
    const float W_I = theta[4],     tau_I = theta[5], I_0 = theta[6],  g = theta[7];
    const float g_EE = theta[8],    g_IE = theta[9], g_EI = theta[10];
    const float aE = theta[11], bE = theta[12], dEc = theta[13];
    const float aI = theta[14], bI = theta[15], dIc = theta[16];
    const float sdt = std_in * sqrtf(DT);

    // lane r (r < RPW) owns row base+r
    float E = 0.f, I = 0.f, cnt0 = 0.f;
    float* Hmy = Hc;
    if (lane < RPW) {
        const int i = base + lane;
        E = x0[i * 2 + 0];
        I = x0[i * 2 + 1];
        cnt0 = cnt[(size_t)i * MAXD];
        Hmy = Hc + (size_t)i * MAXD;
    }

    int h = 0;
    unsigned int e = 0;   // epochs completed (global across batches)

    for (int b = 0; b < NBATCH; ++b) {
        float nE = 0.f, nI = 0.f;
        if (lane < RPW) {
            const int i = base + lane;
            nE = noise[((size_t)b * NN + i) * 2 + 0] * sdt;
            nI = noise[((size_t)b * NN + i) * 2 + 1] * sdt;
            ((float2*)out)[(size_t)b * TS * NN + i] = make_float2(E, I);
        }

        for (int t = 1; t < TS; ++t) {
            h = (h == 0) ? (MAXD - 1) : (h - 1);   // head where E_t will be stored

            // ---- overlap window: rest = sum_{d>=1} cnt_d * H (local only) + its reduce
            float s[RPW];
            #pragma unroll
            for (int r = 0; r < RPW; ++r) s[r] = 0.f;
            #pragma unroll
            for (int k = 0; k < 8; ++k) {
                const int d = lane + k * 64;
                if (d >= 1 && d < MAXD) {
                    int hd = h + d; if (hd >= MAXD) hd -= MAXD;
                    #pragma unroll
                    for (int r = 0; r < RPW; ++r)
                        s[r] = fmaf(cnt[(size_t)(base + r) * MAXD + d],
                                    Hc [(size_t)(base + r) * MAXD + hd], s[r]);
                }
            }
            #pragma unroll
            for (int off = 32; off; off >>= 1) {
                #pragma unroll
                for (int r = 0; r < RPW; ++r) s[r] += __shfl_xor(s[r], off);
            }
            float sv = s[0];
            #pragma unroll
            for (int r = 1; r < RPW; ++r) sv = (lane == r) ? s[r] : sv;

            // ---- poll: all waves published epoch e (dense flags, 2 loads/iter)
            if (e) {
                const unsigned int tgt = e;
                const int m = (lane < 36) ? lane : (lane - 36);  // cover 64..99
                for (;;) {
                    unsigned int f1 = ATLU(&flags[lane]);
                    unsigned int f2 = ATLU(&flags[64 + m]);
                    if (__all((f1 >= tgt) && (f2 >= tgt))) break;
                }
            }
            asm volatile("" ::: "memory");   // keep data loads below the poll

            // ---- fetch exchange vector + matvec (critical path)
            const float* src = deT + (size_t)(e & 1) * NN;
            float p[RPW];
            #pragma unroll
            for (int r = 0; r < RPW; ++r) p[r] = 0.f;
            #pragma unroll
            for (int k = 0; k < NN / 64; ++k) {
                const int j = lane + k * 64;
                const float dv = ATLF(&src[j]);
                #pragma unroll
                for (int r = 0; r < RPW; ++r)
                    p[r] = fmaf(L[(size_t)(base + r) * NN + j], dv, p[r]);
            }
            #pragma unroll
            for (int off = 32; off; off >>= 1) {
                #pragma unroll
                for (int r = 0; r < RPW; ++r) p[r] += __shfl_xor(p[r], off);
            }
            float pv = p[0];
            #pragma unroll
            for (int r = 1; r < RPW; ++r) pv = (lane == r) ? p[r] : pv;

            // ---- update + publish
            if (lane < RPW) {
                const float IE = W_E * I_0 + g_EE * E + g * pv - g_IE * I;
                const float II = W_I * I_0 + g_EI * E - I;
                const float RE = h_tf_dev(aE, bE, dEc, IE);
                const float RI = h_tf_dev(aI, bI, dIc, II);
                const float dEd = -E / tau_E + (1.0f - E) * gamma_E * RE;
                const float dId = -I / tau_I + RI;
                E = E + DT * dEd + nE;
                I = I + DT * dId + nI;
                Hmy[h] = E;                                   // local history push
                ATSF(&deT[(size_t)((e + 1) & 1) * NN + base + lane],
                     (sv + cnt0 * E) * (1.0f / 1600.0f));
            }
            // release: data acked at coherence point before flag becomes visible
            asm volatile("s_waitcnt vmcnt(0)" ::: "memory");
            if (lane == 0) ATSU(&flags[widx], e + 1);
            if (lane < RPW)
                ((float2*)out)[(size_t)(b * TS + t) * NN + base + lane] = make_float2(E, I);
            ++e;
        }
    }

    // ---- finals: x_f then hE_f (logical order from circular buffer)
    const size_t xo2 = (size_t)NBATCH * TS * NN;   // float2 index of x_f
    if (lane < RPW)
        ((float2*)out)[xo2 + base + lane] = make_float2(E, I);
    const size_t ho = 2 * xo2 + 2 * NN;            // float offset of hE_f
    #pragma unroll
    for (int k = 0; k < 8; ++k) {
        const int d = lane + k * 64;
        if (d < MAXD) {
            int hd = h + d; if (hd >= MAXD) hd -= MAXD;
            #pragma unroll
            for (int r = 0; r < RPW; ++r)
                out[ho + (size_t)(base + r) * MAXD + d] =
                    Hc[(size_t)(base + r) * MAXD + hd];
        }
    }
}

extern "C" void kernel_launch(void* const* d_in, const int* in_sizes, int n_in,
                              void* d_out, int out_size, void* d_ws, size_t ws_size,
                              hipStream_t stream) {
    const float* x0     = (const float*)d_in[0];
    const float* hE     = (const float*)d_in[1];
    const float* L      = (const float*)d_in[2];
    const float* theta  = (const float*)d_in[3];
    const float* noise  = (const float*)d_in[4];
    const int*   delays = (const int*)d_in[5];
    float* out = (float*)d_out;

    float* ws  = (float*)d_ws;
    float* cnt = ws;
    float* Hc  = ws + 800000;
    float* deT = ws + 1600000;
    unsigned int* flags = (unsigned int*)(ws + 1603200);

    cnt_kernel<<<NN, 256, 0, stream>>>(delays, cnt);
    init_kernel<<<NN, 64, 0, stream>>>(hE, cnt, Hc, deT, flags);
    dmf_main<<<GBLK, 256, 0, stream>>>(x0, L, theta, noise, out, cnt, Hc, deT, flags);
}

// Round 5
// 13568.008 us; speedup vs baseline: 8.0562x; 8.0562x over previous
//
#include <hip/hip_runtime.h>
#include <math.h>

#define NN 1600
#define MAXD 500
#define TS 500
#define NBATCH 4
#define GBLK 100
#define WAVES 4
#define RPW 4                  // rows per wave; 100*4*4 = 1600
#define DT 0.05f

typedef unsigned int u32;

// ---------------- workspace layout (floats) ----------------
// cnt : [0      , 800000)   N*MAXD delay-count weights
// Hc  : [800000 , 1600000)  circular history, head h (logical d -> (h+d)%MAXD)
// deT : [1600000, 1603200)  double-buffered delayed_E, epoch tag in mantissa LSB

#define ATSF(p,v)  __hip_atomic_store((p), (v), __ATOMIC_RELAXED, __HIP_MEMORY_SCOPE_AGENT)

__device__ __forceinline__ float h_tf_dev(float a, float b, float d, float c) {
    float u   = a * c - b;
    float num = 1e-5f + fabsf(u);
    float den = 1e-5f * d + fabsf(1.0f - expf(-d * u));
    return num / (den + 1e-8f);
}

__global__ void cnt_kernel(const int* __restrict__ delays, float* __restrict__ cnt) {
    __shared__ int hist[MAXD];
    const int i = blockIdx.x;
    for (int d = threadIdx.x; d < MAXD; d += blockDim.x) hist[d] = 0;
    __syncthreads();
    const int* row = delays + (size_t)i * NN;
    for (int j = threadIdx.x; j < NN; j += blockDim.x) atomicAdd(&hist[row[j]], 1);
    __syncthreads();
    for (int d = threadIdx.x; d < MAXD; d += blockDim.x)
        cnt[(size_t)i * MAXD + d] = (float)hist[d];
}

__global__ void init_kernel(const float* __restrict__ hE, const float* __restrict__ cnt,
                            float* __restrict__ Hc, float* deT) {
    const int i = blockIdx.x;     // one wave per row
    const int lane = threadIdx.x; // 64 threads
    float s = 0.f;
    for (int d = lane; d < MAXD; d += 64) {
        float v = hE[(size_t)i * MAXD + d];
        Hc[(size_t)i * MAXD + d] = v;
        s = fmaf(cnt[(size_t)i * MAXD + d], v, s);
    }
    #pragma unroll
    for (int off = 32; off; off >>= 1) s += __shfl_xor(s, off);
    if (lane == 0) {
        // slot 0 = epoch-0 data, tag bit (0>>1)&1 = 0
        u32 u = __float_as_uint(s / 1600.0f) & ~1u;
        ATSF(&deT[i], __uint_as_float(u));
        // slot 1 = invalid marker: epoch 1 expects tag 0, so write LSB=1.
        // Must rewrite every launch (stale tags from a previous replay otherwise).
        ATSF(&deT[NN + i], __uint_as_float(1u));
    }
}

__global__ __launch_bounds__(256, 1) void dmf_main(
        const float* __restrict__ x0, const float* __restrict__ L,
        const float* __restrict__ theta, const float* __restrict__ noise,
        float* __restrict__ out, const float* __restrict__ cnt,
        float* __restrict__ Hc, float* deT) {
    const int lane = threadIdx.x & 63;
    const int wv   = __builtin_amdgcn_readfirstlane(threadIdx.x >> 6);
    const int widx = blockIdx.x * WAVES + wv;   // 0..399
    const int base = widx * RPW;                // first row of this wave

    const float std_in = theta[0],  W_E = theta[1],  tau_E = theta[2], gamma_E = theta[3];
    const float W_I = theta[4],     tau_I = theta[5], I_0 = theta[6],  g = theta[7];
    const float g_EE = theta[8],    g_IE = theta[9], g_EI = theta[10];
    const float aE = theta[11], bE = theta[12], dEc = theta[13];
    const float aI = theta[14], bI = theta[15], dIc = theta[16];
    const float sdt = std_in * sqrtf(DT);

    // lane r (r < RPW) owns row base+r
    float E = 0.f, I = 0.f, cnt0 = 0.f;
    float* Hmy = Hc;
    if (lane < RPW) {
        const int i = base + lane;
        E = x0[i * 2 + 0];
        I = x0[i * 2 + 1];
        cnt0 = cnt[(size_t)i * MAXD];
        Hmy = Hc + (size_t)i * MAXD;
    }

    // delay-count weights in registers (fixed all run); d=0 excluded (added analytically)
    float creg[8][RPW];
    #pragma unroll
    for (int k = 0; k < 8; ++k) {
        const int d = lane + k * 64;
        #pragma unroll
        for (int r = 0; r < RPW; ++r)
            creg[k][r] = (d >= 1 && d < MAXD) ? cnt[(size_t)(base + r) * MAXD + d] : 0.f;
    }

    int h = 0;
    u32 e = 0;   // epochs completed (continuous across batches)

    float4 q[6];
    float  qx;

    for (int b = 0; b < NBATCH; ++b) {
        float nE = 0.f, nI = 0.f;
        if (lane < RPW) {
            const int i = base + lane;
            nE = noise[((size_t)b * NN + i) * 2 + 0] * sdt;
            nI = noise[((size_t)b * NN + i) * 2 + 1] * sdt;
            ((float2*)out)[(size_t)b * TS * NN + i] = make_float2(E, I);
        }

        for (int t = 1; t < TS; ++t) {
            h = (h == 0) ? (MAXD - 1) : (h - 1);   // head where E_t will land

            const float* src = deT + (size_t)(e & 1) * NN;
            const u32 tg = (e >> 1) & 1;

            auto issue_loads = [&]() {
                #pragma unroll
                for (int k = 0; k < 6; ++k) {
                    const float* ap = src + (lane * 4 + k * 256);
                    asm volatile("global_load_dwordx4 %0, %1, off sc0 sc1"
                                 : "=v"(q[k]) : "v"(ap) : "memory");
                }
                const float* at = src + (1536 + lane);
                asm volatile("global_load_dword %0, %1, off sc0 sc1"
                             : "=v"(qx) : "v"(at) : "memory");
            };

            // ---- issue exchange loads FIRST (latency hides under history sum)
            issue_loads();

            // ---- local history sum (d>=1) + reduce, fully overlapped
            float s[RPW];
            #pragma unroll
            for (int r = 0; r < RPW; ++r) s[r] = 0.f;
            #pragma unroll
            for (int k = 0; k < 8; ++k) {
                const int d = lane + k * 64;
                if (d < MAXD) {
                    int hd = h + d; if (hd >= MAXD) hd -= MAXD;
                    #pragma unroll
                    for (int r = 0; r < RPW; ++r)
                        s[r] = fmaf(creg[k][r], Hc[(size_t)(base + r) * MAXD + hd], s[r]);
                }
            }
            #pragma unroll
            for (int off = 32; off; off >>= 1) {
                #pragma unroll
                for (int r = 0; r < RPW; ++r) s[r] += __shfl_xor(s[r], off);
            }
            float sv = s[0];
            #pragma unroll
            for (int r = 1; r < RPW; ++r) sv = (lane == r) ? s[r] : sv;

            // ---- tag-poll: batched, pipelined re-issue with backoff
            for (;;) {
                asm volatile("s_waitcnt vmcnt(0)" ::: "memory");
                __builtin_amdgcn_sched_barrier(0);
                bool ok = ((__float_as_uint(qx) & 1u) == tg);
                #pragma unroll
                for (int k = 0; k < 6; ++k) {
                    ok &= ((__float_as_uint(q[k].x) & 1u) == tg);
                    ok &= ((__float_as_uint(q[k].y) & 1u) == tg);
                    ok &= ((__float_as_uint(q[k].z) & 1u) == tg);
                    ok &= ((__float_as_uint(q[k].w) & 1u) == tg);
                }
                if (__all(ok)) break;
                __builtin_amdgcn_s_sleep(1);
                issue_loads();
            }

            // ---- matvec: L rows (L2-resident, plain cached float4 loads)
            float p[RPW];
            #pragma unroll
            for (int r = 0; r < RPW; ++r) p[r] = 0.f;
            #pragma unroll
            for (int k = 0; k < 6; ++k) {
                #pragma unroll
                for (int r = 0; r < RPW; ++r) {
                    const float4 lv = *reinterpret_cast<const float4*>(
                        &L[(size_t)(base + r) * NN + lane * 4 + k * 256]);
                    p[r] = fmaf(lv.x, q[k].x, p[r]);
                    p[r] = fmaf(lv.y, q[k].y, p[r]);
                    p[r] = fmaf(lv.z, q[k].z, p[r]);
                    p[r] = fmaf(lv.w, q[k].w, p[r]);
                }
            }
            #pragma unroll
            for (int r = 0; r < RPW; ++r)
                p[r] = fmaf(L[(size_t)(base + r) * NN + 1536 + lane], qx, p[r]);
            #pragma unroll
            for (int off = 32; off; off >>= 1) {
                #pragma unroll
                for (int r = 0; r < RPW; ++r) p[r] += __shfl_xor(p[r], off);
            }
            float pv = p[0];
            #pragma unroll
            for (int r = 1; r < RPW; ++r) pv = (lane == r) ? p[r] : pv;

            // ---- update + publish tagged delayed_E for epoch e+1
            const u32 ntg = ((e + 1) >> 1) & 1;
            if (lane < RPW) {
                const float IE = W_E * I_0 + g_EE * E + g * pv - g_IE * I;
                const float II = W_I * I_0 + g_EI * E - I;
                const float RE = h_tf_dev(aE, bE, dEc, IE);
                const float RI = h_tf_dev(aI, bI, dIc, II);
                const float dEd = -E / tau_E + (1.0f - E) * gamma_E * RE;
                const float dId = -I / tau_I + RI;
                E = E + DT * dEd + nE;
                I = I + DT * dId + nI;
                Hmy[h] = E;                                   // local history push
                const float val = (sv + cnt0 * E) * (1.0f / 1600.0f);
                const u32 u = (__float_as_uint(val) & ~1u) | ntg;
                ATSF(&deT[(size_t)((e + 1) & 1) * NN + base + lane], __uint_as_float(u));
                ((float2*)out)[(size_t)(b * TS + t) * NN + base + lane] = make_float2(E, I);
            }
            ++e;
        }
    }

    // ---- finals: x_f then hE_f (logical order from circular buffer)
    const size_t xo2 = (size_t)NBATCH * TS * NN;   // float2 index of x_f
    if (lane < RPW)
        ((float2*)out)[xo2 + base + lane] = make_float2(E, I);
    const size_t ho = 2 * xo2 + 2 * NN;            // float offset of hE_f
    #pragma unroll
    for (int k = 0; k < 8; ++k) {
        const int d = lane + k * 64;
        if (d < MAXD) {
            int hd = h + d; if (hd >= MAXD) hd -= MAXD;
            #pragma unroll
            for (int r = 0; r < RPW; ++r)
                out[ho + (size_t)(base + r) * MAXD + d] =
                    Hc[(size_t)(base + r) * MAXD + hd];
        }
    }
}

extern "C" void kernel_launch(void* const* d_in, const int* in_sizes, int n_in,
                              void* d_out, int out_size, void* d_ws, size_t ws_size,
                              hipStream_t stream) {
    const float* x0     = (const float*)d_in[0];
    const float* hE     = (const float*)d_in[1];
    const float* L      = (const float*)d_in[2];
    const float* theta  = (const float*)d_in[3];
    const float* noise  = (const float*)d_in[4];
    const int*   delays = (const int*)d_in[5];
    float* out = (float*)d_out;

    float* ws  = (float*)d_ws;
    float* cnt = ws;
    float* Hc  = ws + 800000;
    float* deT = ws + 1600000;

    cnt_kernel<<<NN, 256, 0, stream>>>(delays, cnt);
    init_kernel<<<NN, 64, 0, stream>>>(hE, cnt, Hc, deT);
    dmf_main<<<GBLK, 256, 0, stream>>>(x0, L, theta, noise, out, cnt, Hc, deT);
}